// Round 2
// baseline (207.553 us; speedup 1.0000x reference)
//
#include <hip/hip_runtime.h>
#include <hip/hip_fp16.h>

#define NN 8192
#define INF 256
#define OUTF 128
#define LOG2E 1.44269504088896340736f

typedef float f32x4 __attribute__((ext_vector_type(4)));
typedef float f32x16 __attribute__((ext_vector_type(16)));
typedef __fp16 h16x8 __attribute__((ext_vector_type(8)));
typedef __fp16 h16x2 __attribute__((ext_vector_type(2)));
typedef int i32x4 __attribute__((ext_vector_type(4)));

__device__ __forceinline__ void gload_lds16(const void* g, void* l) {
  __builtin_amdgcn_global_load_lds(
      (const __attribute__((address_space(1))) unsigned int*)g,
      (__attribute__((address_space(3))) unsigned int*)l, 16, 0, 0);
}

// ---------------- K0: W (256x128 f32) -> WT_perm f16 [head][col][kb16][2hh][8slots]
__global__ __launch_bounds__(256) void k0_wt(const float* __restrict__ W1,
                                             const float* __restrict__ W2,
                                             __fp16* __restrict__ WT) {
  int m = blockIdx.x * 256 + threadIdx.x;  // 8192 chunks of 16B
  int h = m >> 12;
  int r = m & 4095;
  int c = r >> 5;
  int kb = (r >> 1) & 15;
  int hh = r & 1;
  const float* W = h ? W2 : W1;
  float v[8];
#pragma unroll
  for (int s = 0; s < 8; ++s) {
    int koff = 4 * hh + (s & 3) + 8 * (s >> 2);  // two k-4 groups, blocks 8 apart
    v[s] = W[(kb * 16 + koff) * OUTF + c];
  }
  union { h16x2 h2[4]; i32x4 q; } u;
  u.h2[0] = __builtin_amdgcn_cvt_pkrtz(v[0], v[1]);
  u.h2[1] = __builtin_amdgcn_cvt_pkrtz(v[2], v[3]);
  u.h2[2] = __builtin_amdgcn_cvt_pkrtz(v[4], v[5]);
  u.h2[3] = __builtin_amdgcn_cvt_pkrtz(v[6], v[7]);
  *(i32x4*)(WT + (size_t)h * 32768 + c * 256 + kb * 16 + hh * 8) = u.q;
}

// ---------------- K1: h = inp@W (both heads) via MFMA f16; emits hT_perm f16,
// src' = (h@a_src)*log2e, dst' = (h@a_dst)*log2e
__global__ __launch_bounds__(128) void k1_h(
    const float* __restrict__ inp, const __fp16* __restrict__ WT,
    const float* __restrict__ a1, const float* __restrict__ a2,
    __fp16* __restrict__ hT, float* __restrict__ S, float* __restrict__ D) {
  __shared__ __align__(16) float hl[2][32][136];
  int tid = threadIdx.x;
  int w = tid >> 6;           // wave = head
  int l = tid & 63;
  int lr = l & 31, g = l >> 5;
  int i0 = blockIdx.x * 32;
  const __fp16* WTh = WT + (size_t)w * 32768;
  f32x16 acc[4];
#pragma unroll
  for (int nf = 0; nf < 4; ++nf)
#pragma unroll
    for (int e = 0; e < 16; ++e) acc[nf][e] = 0.0f;
  const float* ip = inp + (size_t)(i0 + lr) * INF;
#pragma unroll
  for (int kb = 0; kb < 16; ++kb) {
    f32x4 q0 = *(const f32x4*)(ip + kb * 16 + 4 * g);
    f32x4 q1 = *(const f32x4*)(ip + kb * 16 + 8 + 4 * g);
    union { h16x2 h2[4]; h16x8 h8; } ua;
    ua.h2[0] = __builtin_amdgcn_cvt_pkrtz(q0[0], q0[1]);
    ua.h2[1] = __builtin_amdgcn_cvt_pkrtz(q0[2], q0[3]);
    ua.h2[2] = __builtin_amdgcn_cvt_pkrtz(q1[0], q1[1]);
    ua.h2[3] = __builtin_amdgcn_cvt_pkrtz(q1[2], q1[3]);
#pragma unroll
    for (int nf = 0; nf < 4; ++nf) {
      h16x8 b = *(const h16x8*)(WTh + (nf * 32 + lr) * 256 + kb * 16 + g * 8);
      acc[nf] = __builtin_amdgcn_mfma_f32_32x32x16_f16(ua.h8, b, acc[nf], 0, 0, 0);
    }
  }
  // dump acc (C layout: col=l&31, row=(r&3)+8*(r>>2)+4*(l>>5)) to LDS
#pragma unroll
  for (int nf = 0; nf < 4; ++nf)
#pragma unroll
    for (int r = 0; r < 16; ++r) {
      int row = (r & 3) + 8 * (r >> 2) + 4 * g;
      hl[w][row][nf * 32 + lr] = acc[nf][r];
    }
  __syncthreads();
  // src/dst dot per row (fp32 exact path)
  const float* av = w ? a2 : a1;
  float s = 0.f, d = 0.f;
#pragma unroll
  for (int cc = 0; cc < 64; cc += 4) {
    int c = g * 64 + cc;
    f32x4 hv = *(const f32x4*)&hl[w][lr][c];
    f32x4 as = *(const f32x4*)(av + c);
    f32x4 ad = *(const f32x4*)(av + 128 + c);
    s += hv[0] * as[0] + hv[1] * as[1] + hv[2] * as[2] + hv[3] * as[3];
    d += hv[0] * ad[0] + hv[1] * ad[1] + hv[2] * ad[2] + hv[3] * ad[3];
  }
  s += __shfl_xor(s, 32);
  d += __shfl_xor(d, 32);
  if (g == 0) {
    S[(size_t)w * NN + i0 + lr] = s * LOG2E;
    D[(size_t)w * NN + i0 + lr] = d * LOG2E;
  }
  // hT_perm extraction: [head][jb16][col][2hh][8slots] f16, 16B units
  __fp16* hTh = hT + (size_t)w * (NN * OUTF);
#pragma unroll
  for (int it = 0; it < 8; ++it) {
    int m = it * 64 + l;
    int col = (m >> 1) & 127, hh = m & 1, jb = m >> 8;
    float v[8];
#pragma unroll
    for (int s2 = 0; s2 < 8; ++s2) {
      int off = 4 * hh + (s2 & 3) + 8 * (s2 >> 2);
      v[s2] = hl[w][jb * 16 + off][col];
    }
    union { h16x2 h2[4]; i32x4 q; } u2;
    u2.h2[0] = __builtin_amdgcn_cvt_pkrtz(v[0], v[1]);
    u2.h2[1] = __builtin_amdgcn_cvt_pkrtz(v[2], v[3]);
    u2.h2[2] = __builtin_amdgcn_cvt_pkrtz(v[4], v[5]);
    u2.h2[3] = __builtin_amdgcn_cvt_pkrtz(v[6], v[7]);
    *(i32x4*)(hTh + (size_t)((i0 >> 4) + jb) * 2048 + (col * 2 + hh) * 8) = u2.q;
  }
}

// ---------------- K1c: gmax' per head
__global__ __launch_bounds__(256) void k1c_gmax(const float* __restrict__ D,
                                                float* __restrict__ GM) {
  __shared__ float r1[256], r2[256];
  int t = threadIdx.x;
  float m1 = -1e30f, m2 = -1e30f;
  for (int i = t; i < NN; i += 256) {
    m1 = fmaxf(m1, D[i]);
    m2 = fmaxf(m2, D[NN + i]);
  }
  r1[t] = m1; r2[t] = m2;
  __syncthreads();
  for (int s = 128; s > 0; s >>= 1) {
    if (t < s) { r1[t] = fmaxf(r1[t], r1[t + s]); r2[t] = fmaxf(r2[t], r2[t + s]); }
    __syncthreads();
  }
  if (t == 0) { GM[0] = r1[0]; GM[1] = r2[0]; }
}

// ---------------- K2: fused mask+softmax-numer/denom+PV, both heads
// grid 256 = 64 rowblocks(BM=128) x 4 j-splits; 8 waves = (head, rowhalf, phase)
__global__ __launch_bounds__(512, 2) void k2_attn(
    const int* __restrict__ adj, const __fp16* __restrict__ hT,
    const float* __restrict__ S, const float* __restrict__ D,
    const float* __restrict__ GM, float* __restrict__ NUM, float* __restrict__ DEN) {
  __shared__ __align__(16) char smem[133120];  // 2 x (2 heads x 32KB) tiles + 2 x 1KB dst
  int tid = threadIdx.x;
  int w = tid >> 6;
  int l = tid & 63;
  int lr = l & 31, g = l >> 5;
  int h = w >> 2, rh = (w >> 1) & 1, p = w & 1;
  int rb = blockIdx.x >> 2, js = blockIdx.x & 3;
  int i0 = rb * 128;
  int jbase = js * 2048;

  int row0 = i0 + rh * 64 + lr;
  int row1 = row0 + 32;
  float s0 = S[(size_t)h * NN + row0];
  float s1 = S[(size_t)h * NN + row1];
  float gm = GM[h];
  float v0 = s0 + gm, v1 = s1 + gm;
  float c0 = -(fmaxf(v0, 0.2f * v0) + 1000.0f);
  float c1 = -(fmaxf(v1, 0.2f * v1) + 1000.0f);

  f32x16 acc[2][4];
#pragma unroll
  for (int f = 0; f < 2; ++f)
#pragma unroll
    for (int nf = 0; nf < 4; ++nf)
#pragma unroll
      for (int e = 0; e < 16; ++e) acc[f][nf][e] = 0.0f;
  float dsum0 = 0.f, dsum1 = 0.f;

  const int* adjr0 = adj + (size_t)row0 * NN + jbase + 4 * g;
  const int* adjr1 = adj + (size_t)row1 * NN + jbase + 4 * g;

  auto STAGE = [&](int t, int b) {
#pragma unroll
    for (int q = 0; q < 8; ++q) {
      int id = w * 8 + q;
      int hh = id >> 5;
      int off = (id & 31) * 1024;
      const char* gs = (const char*)hT + (size_t)hh * 2097152 +
                       (size_t)(js * 128 + t * 8) * 4096 + off + (size_t)l * 16;
      char* ld = smem + b * 65536 + hh * 32768 + off;  // wave-uniform dest
      gload_lds16(gs, ld);
    }
    if (w == 0) {  // dst' tiles, both heads: 1KB
      const float* gd = D + (size_t)(l >> 5) * NN + jbase + t * 128 + (l & 31) * 4;
      char* ld = smem + 131072 + b * 1024;
      gload_lds16(gd, ld);
    }
  };

  struct Adj4 { i32x4 v[4]; };
  auto LOAD_ADJ = [&](int t, int ks) {
    Adj4 A;
    int o = t * 128 + ks * 16;
    A.v[0] = *(const i32x4*)(adjr0 + o);
    A.v[1] = *(const i32x4*)(adjr0 + o + 8);
    A.v[2] = *(const i32x4*)(adjr1 + o);
    A.v[3] = *(const i32x4*)(adjr1 + o + 8);
    return A;
  };

  auto COMPUTE = [&](int ks, int b, const Adj4& A) {
    const float* db = (const float*)(smem + 131072) + b * 256 + h * 128;
    f32x4 d0 = *(const f32x4*)(db + ks * 16 + 4 * g);
    f32x4 d1 = *(const f32x4*)(db + ks * 16 + 8 + 4 * g);
    const char* hb = smem + b * 65536 + h * 32768 + ks * 4096 + g * 16;
    h16x8 Bf[4];
#pragma unroll
    for (int nf = 0; nf < 4; ++nf)
      Bf[nf] = *(const h16x8*)(hb + nf * 1024 + lr * 32);
    h16x8 PA[2];
#pragma unroll
    for (int f = 0; f < 2; ++f) {
      float sf = f ? s1 : s0;
      float cf = f ? c1 : c0;
      float pv[8];
#pragma unroll
      for (int kb = 0; kb < 2; ++kb) {
        f32x4 dd = kb ? d1 : d0;
        i32x4 aa = A.v[f * 2 + kb];
#pragma unroll
        for (int q = 0; q < 4; ++q) {
          float tt = sf + dd[q];
          float u = fmaxf(tt, 0.2f * tt);                  // LeakyReLU (log2-scaled)
          float mk = fmaf((float)aa[q], 1000.0f, cf);      // -m' or -m'-1000
          pv[kb * 4 + q] = exp2f(u + mk);                  // masked -> exact 0
        }
      }
      float ds = pv[0] + pv[1] + pv[2] + pv[3] + pv[4] + pv[5] + pv[6] + pv[7];
      if (f == 0) dsum0 += ds; else dsum1 += ds;
      union { h16x2 h2[4]; h16x8 h8; } up;
      up.h2[0] = __builtin_amdgcn_cvt_pkrtz(pv[0], pv[1]);
      up.h2[1] = __builtin_amdgcn_cvt_pkrtz(pv[2], pv[3]);
      up.h2[2] = __builtin_amdgcn_cvt_pkrtz(pv[4], pv[5]);
      up.h2[3] = __builtin_amdgcn_cvt_pkrtz(pv[6], pv[7]);
      PA[f] = up.h8;
    }
#pragma unroll
    for (int f = 0; f < 2; ++f)
#pragma unroll
      for (int nf = 0; nf < 4; ++nf)
        acc[f][nf] = __builtin_amdgcn_mfma_f32_32x32x16_f16(PA[f], Bf[nf], acc[f][nf], 0, 0, 0);
  };

  STAGE(0, 0);
  Adj4 Ac = LOAD_ADJ(0, p);
  __syncthreads();
#pragma unroll 2
  for (int t = 0; t < 16; ++t) {
    int b = t & 1;
    STAGE((t + 1) & 15, b ^ 1);       // prefetch next tile into other buffer
    Adj4 An = LOAD_ADJ(t, p + 2);     // 2-deep adj register prefetch
    COMPUTE(p, b, Ac);
    Ac = LOAD_ADJ(t, p + 4);
    COMPUTE(p + 2, b, An);
    An = LOAD_ADJ(t, p + 6);
    COMPUTE(p + 4, b, Ac);
    Ac = LOAD_ADJ((t + 1) & 15, p);
    COMPUTE(p + 6, b, An);
    __syncthreads();
  }

  // epilogue: denom lane-halves, phase merge through LDS, coalesced partial write
  dsum0 += __shfl_xor(dsum0, 32);
  dsum1 += __shfl_xor(dsum1, 32);
  int pr = w >> 1;  // (h,rh) pair
  float* mb = (float*)(smem + pr * 32768);
  float* denb = (float*)(smem + 131072);
  if (p == 1) {
#pragma unroll
    for (int f = 0; f < 2; ++f)
#pragma unroll
      for (int nf = 0; nf < 4; ++nf)
#pragma unroll
        for (int r = 0; r < 16; ++r) {
          int row = f * 32 + (r & 3) + 8 * (r >> 2) + 4 * g;
          mb[row * 128 + nf * 32 + lr] = acc[f][nf][r];
        }
    if (g == 0) {
      denb[pr * 64 + lr] = dsum0;
      denb[pr * 64 + 32 + lr] = dsum1;
    }
  }
  __syncthreads();
  if (p == 0) {
#pragma unroll
    for (int f = 0; f < 2; ++f)
#pragma unroll
      for (int nf = 0; nf < 4; ++nf)
#pragma unroll
        for (int r = 0; r < 16; ++r) {
          int row = f * 32 + (r & 3) + 8 * (r >> 2) + 4 * g;
          mb[row * 128 + nf * 32 + lr] += acc[f][nf][r];
        }
    if (g == 0) {
      denb[pr * 64 + lr] += dsum0;
      denb[pr * 64 + 32 + lr] += dsum1;
    }
  }
  __syncthreads();
  for (int pr2 = 0; pr2 < 4; ++pr2) {
    const f32x4* srcp = (const f32x4*)(smem + pr2 * 32768);
    f32x4* dstp = (f32x4*)(NUM + ((size_t)(js * 2 + (pr2 >> 1)) * NN + i0 + (pr2 & 1) * 64) * 128);
#pragma unroll
    for (int q = 0; q < 4; ++q) dstp[q * 512 + tid] = srcp[q * 512 + tid];
  }
  if (tid < 256) {
    int pr3 = tid >> 6, rr = tid & 63;
    DEN[(size_t)(js * 2 + (pr3 >> 1)) * NN + i0 + (pr3 & 1) * 64 + rr] =
        ((const float*)(smem + 131072))[pr3 * 64 + rr];
  }
}

// ---------------- K3: merge js partials, combine heads, ELU
__global__ __launch_bounds__(256) void k3_out(const float* __restrict__ NUM,
                                              const float* __restrict__ DEN,
                                              float* __restrict__ out) {
  int gid = blockIdx.x * 256 + threadIdx.x;  // 262144
  int i = gid >> 5;
  int c4 = (gid & 31) * 4;
  f32x4 n1 = {0.f, 0.f, 0.f, 0.f}, n2 = {0.f, 0.f, 0.f, 0.f};
  float d1 = 0.f, d2 = 0.f;
#pragma unroll
  for (int js = 0; js < 4; ++js) {
    n1 += *(const f32x4*)(NUM + ((size_t)(js * 2 + 0) * NN + i) * 128 + c4);
    n2 += *(const f32x4*)(NUM + ((size_t)(js * 2 + 1) * NN + i) * 128 + c4);
    d1 += DEN[(size_t)(js * 2 + 0) * NN + i];
    d2 += DEN[(size_t)(js * 2 + 1) * NN + i];
  }
  float r1 = 1.0f / d1, r2 = 0.5f / d2;
  f32x4 o;
#pragma unroll
  for (int e = 0; e < 4; ++e) {
    float x = n1[e] * r1 + n2[e] * r2;
    o[e] = x > 0.f ? x : (exp2f(x * LOG2E) - 1.0f);
  }
  *(f32x4*)(out + (size_t)i * 128 + c4) = o;
}

extern "C" void kernel_launch(void* const* d_in, const int* in_sizes, int n_in,
                              void* d_out, int out_size, void* d_ws, size_t ws_size,
                              hipStream_t stream) {
  const float* inp = (const float*)d_in[0];
  const int* adj = (const int*)d_in[1];
  const float* W1 = (const float*)d_in[2];
  const float* a1 = (const float*)d_in[3];
  const float* W2 = (const float*)d_in[4];
  const float* a2 = (const float*)d_in[5];
  float* out = (float*)d_out;
  char* ws = (char*)d_ws;
  // ws layout (needs ~38.3 MB):
  __fp16* WT = (__fp16*)(ws);                  // 131072 B
  __fp16* hT = (__fp16*)(ws + 131072);         // 4 MB
  float* S = (float*)(ws + 4325376);           // 64 KB  (src', 2 heads)
  float* D = (float*)(ws + 4390912);           // 64 KB  (dst', 2 heads)
  float* GM = (float*)(ws + 4456448);          // pad to 256
  float* NUM = (float*)(ws + 4456704);         // 33554432 B
  float* DEN = (float*)(ws + 38011136);        // 262144 B

  k0_wt<<<dim3(32), dim3(256), 0, stream>>>(W1, W2, WT);
  k1_h<<<dim3(256), dim3(128), 0, stream>>>(inp, WT, a1, a2, hT, S, D);
  k1c_gmax<<<dim3(1), dim3(256), 0, stream>>>(D, GM);
  k2_attn<<<dim3(256), dim3(512), 0, stream>>>(adj, hT, S, D, GM, NUM, DEN);
  k3_out<<<dim3(1024), dim3(256), 0, stream>>>(NUM, DEN, out);
}